// Round 5
// baseline (112.679 us; speedup 1.0000x reference)
//
#include <hip/hip_runtime.h>
#include <hip/hip_bf16.h>
#include <math.h>

// Problem constants
#define B_  2
#define N_  1024
#define DIM_ 768
#define H_  8
#define DH_ 64
#define PD_ 4
#define NPROJ 1824            // 3*512 + 3*96
#define NPAD  1920            // padded to 15*128
#define BH_ (B_*H_)           // 16
#define FDIM 640              // output feature dim

// ws layout (float offsets)
#define OFF_RS   0u
#define OFF_RP   (OFF_RS + (size_t)BH_*N_*DH_)          // 1048576
#define OFF_PRAW (OFF_RP + (size_t)BH_*N_*12)           // +196608
#define OFF_QA   (OFF_PRAW + (size_t)B_*N_*288)         // +589824 ; bf16 [16][1024][96]
#define OFF_KA   (OFF_QA + (size_t)BH_*N_*96/2)         // +786432
#define OFF_VT   (OFF_KA + (size_t)BH_*N_*96/2)         // bf16 [16][80][1024]
#define OFF_XB   (OFF_VT + (size_t)BH_*80*N_/2)         // bf16 x  (later: fb)
#define OFF_WB   (OFF_XB + (size_t)B_*N_*DIM_/2)        // bf16 packed W (later: wob)
// reuse after projection:
#define OFF_FB   OFF_XB       // bf16 [2048][640]
#define OFF_WOB  OFF_WB       // bf16 [768][640]

typedef __attribute__((ext_vector_type(8))) short bf16x8;
typedef __attribute__((ext_vector_type(4))) float f32x4;

__device__ __forceinline__ float dot4(float4 a, float4 b) {
    return a.x*b.x + a.y*b.y + a.z*b.z + a.w*b.w;
}
__device__ __forceinline__ unsigned short f2bf(float f) {
    __hip_bfloat16 h = __float2bfloat16(f);
    return *reinterpret_cast<unsigned short*>(&h);
}

// ---------------------------------------------------------------------------
// convert x -> bf16
// ---------------------------------------------------------------------------
__global__ __launch_bounds__(256) void k_cvt_x(
    const float* __restrict__ x, unsigned short* __restrict__ xb)
{
    int i = blockIdx.x * 256 + threadIdx.x;
    if (i >= (B_*N_*DIM_)/4) return;
    float4 v = reinterpret_cast<const float4*>(x)[i];
    ushort4 o;
    o.x = f2bf(v.x); o.y = f2bf(v.y); o.z = f2bf(v.z); o.w = f2bf(v.w);
    reinterpret_cast<ushort4*>(xb)[i] = o;
}

// ---------------------------------------------------------------------------
// pack 6 weight mats into wb[1920][768] bf16
// ---------------------------------------------------------------------------
__global__ __launch_bounds__(256) void k_cvt_w(
    const float* __restrict__ Wsq, const float* __restrict__ Wsk,
    const float* __restrict__ Wsv, const float* __restrict__ Wpq,
    const float* __restrict__ Wpk, const float* __restrict__ Wpv,
    unsigned short* __restrict__ wb)
{
    int i = blockIdx.x * 256 + threadIdx.x;
    if (i >= (NPAD*DIM_)/4) return;
    int row = i / (DIM_/4);
    int c4  = i % (DIM_/4);
    ushort4 o;
    if (row >= NPROJ) {
        o.x = o.y = o.z = o.w = 0;
    } else {
        const float* W;
        if      (row < 512)  W = Wsq + (size_t)row*DIM_;
        else if (row < 1024) W = Wsk + (size_t)(row-512)*DIM_;
        else if (row < 1536) W = Wsv + (size_t)(row-1024)*DIM_;
        else if (row < 1632) W = Wpq + (size_t)(row-1536)*DIM_;
        else if (row < 1728) W = Wpk + (size_t)(row-1632)*DIM_;
        else                 W = Wpv + (size_t)(row-1728)*DIM_;
        float4 v = reinterpret_cast<const float4*>(W)[c4];
        o.x = f2bf(v.x); o.y = f2bf(v.y); o.z = f2bf(v.z); o.w = f2bf(v.w);
    }
    reinterpret_cast<ushort4*>(wb)[i] = o;
}

// ---------------------------------------------------------------------------
// convert Wout[768][640] -> bf16
// ---------------------------------------------------------------------------
__global__ __launch_bounds__(256) void k_cvt_wout(
    const float* __restrict__ Wout, unsigned short* __restrict__ wob)
{
    int i = blockIdx.x * 256 + threadIdx.x;
    if (i >= (DIM_*FDIM)/4) return;
    float4 v = reinterpret_cast<const float4*>(Wout)[i];
    ushort4 o;
    o.x = f2bf(v.x); o.y = f2bf(v.y); o.z = f2bf(v.z); o.w = f2bf(v.w);
    reinterpret_cast<ushort4*>(wob)[i] = o;
}

// ---------------------------------------------------------------------------
// K1: projection GEMM via MFMA; epilogue writes Qa/Ka/Vt (bf16) + praw (f32)
// ---------------------------------------------------------------------------
__global__ __launch_bounds__(256) void k_proj_mfma(
    const unsigned short* __restrict__ xb,
    const unsigned short* __restrict__ wb,
    float* __restrict__ ws)
{
    __shared__ unsigned short sAB[2*128*32];
    const int tid  = threadIdx.x;
    const int lane = tid & 63;
    const int wid  = tid >> 6;
    const int mt = blockIdx.x & 15;
    const int nt = blockIdx.x >> 4;
    const int row0 = mt*128;
    const int col0 = nt*128;
    const int wr = (wid >> 1)*64;
    const int wc = (wid & 1)*64;

    f32x4 acc[4][4];
    #pragma unroll
    for (int m = 0; m < 4; ++m)
        #pragma unroll
        for (int n = 0; n < 4; ++n) acc[m][n] = (f32x4){0.f,0.f,0.f,0.f};

    for (int kt = 0; kt < DIM_/32; ++kt) {
        __syncthreads();
        #pragma unroll
        for (int t = 0; t < 4; ++t) {
            int chunk = t*4 + wid;
            int tile  = chunk >> 3;
            int crow  = (chunk & 7) * 16;
            int grow  = (tile ? col0 : row0) + crow + (lane >> 2);
            const unsigned short* gsrc = (tile ? wb : xb)
                + (size_t)grow*DIM_ + kt*32 + (lane & 3)*8;
            __builtin_amdgcn_global_load_lds(
                (const __attribute__((address_space(1))) void*)gsrc,
                (__attribute__((address_space(3))) void*)(sAB + chunk*512),
                16, 0, 0);
        }
        __syncthreads();

        bf16x8 a[4], b[4];
        #pragma unroll
        for (int m = 0; m < 4; ++m)
            a[m] = *reinterpret_cast<const bf16x8*>(
                sAB + ((wr + m*16 + (lane & 15))*32 + (lane >> 4)*8));
        #pragma unroll
        for (int n = 0; n < 4; ++n)
            b[n] = *reinterpret_cast<const bf16x8*>(
                sAB + 128*32 + ((wc + n*16 + (lane & 15))*32 + (lane >> 4)*8));
        #pragma unroll
        for (int m = 0; m < 4; ++m)
            #pragma unroll
            for (int n = 0; n < 4; ++n)
                acc[m][n] = __builtin_amdgcn_mfma_f32_16x16x32_bf16(
                    a[m], b[n], acc[m][n], 0, 0, 0);
    }

    unsigned short* qa = (unsigned short*)(ws + OFF_QA);
    unsigned short* ka = (unsigned short*)(ws + OFF_KA);
    unsigned short* vt = (unsigned short*)(ws + OFF_VT);
    float* praw = ws + OFF_PRAW;
    const float ss = 0.08838834764831845f;   // (2*64)^-0.5

    #pragma unroll
    for (int n = 0; n < 4; ++n) {
        int o = col0 + wc + n*16 + (lane & 15);
        if (o >= NPROJ) continue;
        #pragma unroll
        for (int m = 0; m < 4; ++m) {
            #pragma unroll
            for (int j = 0; j < 4; ++j) {
                int r = row0 + wr + m*16 + (lane >> 4)*4 + j;
                int bb = r >> 10, nn = r & (N_-1);
                float v = acc[m][n][j];
                if (o < 512) {
                    int h = o >> 6, c = o & 63;
                    qa[((size_t)(bb*H_ + h)*N_ + nn)*96 + c] = f2bf(v*ss);
                } else if (o < 1024) {
                    int oo = o - 512; int h = oo >> 6, c = oo & 63;
                    ka[((size_t)(bb*H_ + h)*N_ + nn)*96 + c] = f2bf(v);
                } else if (o < 1536) {
                    int oo = o - 1024; int h = oo >> 6, c = oo & 63;
                    vt[((size_t)(bb*H_ + h)*80 + c)*N_ + nn] = f2bf(v);
                } else {
                    praw[(size_t)r*288 + (o - 1536)] = v;
                }
            }
        }
    }
}

// ---------------------------------------------------------------------------
// K2: rotate points, q2/k2, write Qa/Ka tails + Vt point rows (+ zero pads)
// ---------------------------------------------------------------------------
__global__ __launch_bounds__(128) void k_prep(
    const float* __restrict__ rot_g,
    const float* __restrict__ trans_g,
    const float* __restrict__ pw_g,
    float* __restrict__ ws)
{
    __shared__ float R[9], T[3];
    __shared__ float rot[3][8][4][3];
    __shared__ float p2[2][8][4];
    __shared__ float q2t[8], k2t[8], coefs[8];
    const int tid = threadIdx.x;
    const int row = blockIdx.x;
    const int b = row >> 10, n = row & (N_-1);

    if (tid < 9)  R[tid] = rot_g[(size_t)row*9 + tid];
    if (tid >= 9 && tid < 12) T[tid-9] = trans_g[(size_t)row*3 + (tid-9)];
    if (tid >= 16 && tid < 24) {
        float pw = pw_g[tid-16];
        coefs[tid-16] = 0.5f * log1pf(__expf(pw)) * (1.0f/6.0f);
    }
    __syncthreads();
    if (tid < 96) {
        int which = tid >> 5, idx = tid & 31;
        int h = idx >> 2, pd = idx & 3;
        const float* p = ws + OFF_PRAW + (size_t)row*288 + which*96 + h*12 + pd*3;
        float px = p[0], py = p[1], pz = p[2];
        float c0 = R[0]*px + R[1]*py + R[2]*pz + T[0];
        float c1 = R[3]*px + R[4]*py + R[5]*pz + T[1];
        float c2 = R[6]*px + R[7]*py + R[8]*pz + T[2];
        rot[which][h][pd][0] = c0;
        rot[which][h][pd][1] = c1;
        rot[which][h][pd][2] = c2;
        if (which < 2) p2[which][h][pd] = c0*c0 + c1*c1 + c2*c2;
    }
    __syncthreads();
    if (tid < 16) {
        int w = tid >> 3, h = tid & 7;
        float s = p2[w][h][0] + p2[w][h][1] + p2[w][h][2] + p2[w][h][3];
        if (w) k2t[h] = s; else q2t[h] = s;
    }
    __syncthreads();

    unsigned short* qa = (unsigned short*)(ws + OFF_QA);
    unsigned short* ka = (unsigned short*)(ws + OFF_KA);
    unsigned short* vt = (unsigned short*)(ws + OFF_VT);

    for (int i = tid; i < 256; i += 128) {
        int h = i >> 5, c = i & 31;
        float qv, kv;
        if (c < 12)      { qv = rot[0][h][c/3][c%3] * 2.f * coefs[h]; kv = rot[1][h][c/3][c%3]; }
        else if (c == 12){ qv = q2t[h];  kv = -coefs[h]; }
        else if (c == 13){ qv = 1.f;     kv = -coefs[h]*k2t[h]; }
        else             { qv = 0.f;     kv = 0.f; }
        size_t base = ((size_t)(b*H_ + h)*N_ + n)*96 + 64 + c;
        qa[base] = f2bf(qv);
        ka[base] = f2bf(kv);
    }
    {
        int h = tid >> 4, r = tid & 15;
        float vv = (r < 12) ? rot[2][h][r/3][r%3] : 0.f;
        vt[((size_t)(b*H_ + h)*80 + 64 + r)*N_ + n] = f2bf(vv);
    }
}

// ---------------------------------------------------------------------------
// K3: MFMA flash attention, K/V read directly from global (L2-resident).
// grid = 512 blocks, 256 threads; wave = 16 q-rows x 8 k-tiles (2-way k-split).
// ---------------------------------------------------------------------------
#define VPAD 72
__global__ __launch_bounds__(256) void k_attn_mfma(
    const unsigned short* __restrict__ qa_g,
    const unsigned short* __restrict__ ka_g,
    const unsigned short* __restrict__ vt_g,
    float* __restrict__ ws)
{
    __shared__ unsigned short sP[4][16*VPAD];
    __shared__ float sMrg[32*80];
    __shared__ float sML[32*2];

    const int tid  = threadIdx.x;
    const int lane = tid & 63;
    const int wid  = tid >> 6;
    const int lo = lane & 15;
    const int hi = lane >> 4;
    const int bh = blockIdx.x >> 5;
    const int qt = blockIdx.x & 31;
    const int q0 = qt * 32;
    const int mrow = (wid & 1) * 16;
    const int half = wid >> 1;

    const unsigned short* Qa = qa_g + (size_t)bh*N_*96;
    const unsigned short* Ka = ka_g + (size_t)bh*N_*96;
    const unsigned short* Vt = vt_g + (size_t)bh*80*N_;

    bf16x8 qfr[3];
    {
        int qrow = q0 + mrow + lo;
        #pragma unroll
        for (int c = 0; c < 3; ++c)
            qfr[c] = *reinterpret_cast<const bf16x8*>(
                Qa + (size_t)qrow*96 + c*32 + hi*8);
    }

    f32x4 acc[5];
    #pragma unroll
    for (int d = 0; d < 5; ++d) acc[d] = (f32x4){0.f,0.f,0.f,0.f};
    float m[4] = {-1e30f,-1e30f,-1e30f,-1e30f};
    float l[4] = {0.f,0.f,0.f,0.f};

    for (int it = 0; it < 8; ++it) {
        const int j0 = (half*8 + it)*64;

        // S = Qa . Ka^T  — K fragments straight from global (L2)
        f32x4 s[4];
        #pragma unroll
        for (int t = 0; t < 4; ++t) s[t] = (f32x4){0.f,0.f,0.f,0.f};
        #pragma unroll
        for (int c = 0; c < 3; ++c) {
            bf16x8 kb[4];
            #pragma unroll
            for (int t = 0; t < 4; ++t)
                kb[t] = *reinterpret_cast<const bf16x8*>(
                    Ka + (size_t)(j0 + t*16 + lo)*96 + c*32 + hi*8);
            #pragma unroll
            for (int t = 0; t < 4; ++t)
                s[t] = __builtin_amdgcn_mfma_f32_16x16x32_bf16(qfr[c], kb[t], s[t], 0, 0, 0);
        }

        // online softmax; rows r: i = hi*4 + r, cols j = t*16 + lo
        float scl[4];
        #pragma unroll
        for (int r = 0; r < 4; ++r) {
            float v = fmaxf(fmaxf(s[0][r], s[1][r]), fmaxf(s[2][r], s[3][r]));
            v = fmaxf(v, __shfl_xor(v, 1));
            v = fmaxf(v, __shfl_xor(v, 2));
            v = fmaxf(v, __shfl_xor(v, 4));
            v = fmaxf(v, __shfl_xor(v, 8));
            float mn = fmaxf(m[r], v);
            scl[r] = __expf(m[r] - mn);
            m[r] = mn;
        }
        float ps[4] = {0.f,0.f,0.f,0.f};
        #pragma unroll
        for (int t = 0; t < 4; ++t) {
            #pragma unroll
            for (int r = 0; r < 4; ++r) {
                float p = __expf(s[t][r] - m[r]);
                ps[r] += p;
                sP[wid][(hi*4 + r)*VPAD + t*16 + lo] = f2bf(p);
            }
        }
        #pragma unroll
        for (int r = 0; r < 4; ++r) {
            float v = ps[r];
            v += __shfl_xor(v, 1);
            v += __shfl_xor(v, 2);
            v += __shfl_xor(v, 4);
            v += __shfl_xor(v, 8);
            l[r] = l[r]*scl[r] + v;
        }
        #pragma unroll
        for (int d = 0; d < 5; ++d)
            #pragma unroll
            for (int r = 0; r < 4; ++r) acc[d][r] *= scl[r];

        // PV: O += P . V — V fragments straight from global (L2)
        #pragma unroll
        for (int kk = 0; kk < 2; ++kk) {
            bf16x8 pa = *reinterpret_cast<const bf16x8*>(
                &sP[wid][lo*VPAD + kk*32 + hi*8]);
            #pragma unroll
            for (int dt = 0; dt < 5; ++dt) {
                bf16x8 vb = *reinterpret_cast<const bf16x8*>(
                    Vt + (size_t)(dt*16 + lo)*N_ + j0 + kk*32 + hi*8);
                acc[dt] = __builtin_amdgcn_mfma_f32_16x16x32_bf16(pa, vb, acc[dt], 0, 0, 0);
            }
        }
    }

    // merge the two k-halves
    __syncthreads();
    if (half == 1) {
        #pragma unroll
        for (int r = 0; r < 4; ++r) {
            int rl = mrow + hi*4 + r;
            #pragma unroll
            for (int dt = 0; dt < 5; ++dt)
                sMrg[rl*80 + dt*16 + lo] = acc[dt][r];
            if (lo == 0) { sML[rl*2] = m[r]; sML[rl*2+1] = l[r]; }
        }
    }
    __syncthreads();
    if (half == 0) {
        float* ws_rs = ws + OFF_RS + (size_t)bh*N_*DH_;
        float* ws_rp = ws + OFF_RP + (size_t)bh*N_*12;
        #pragma unroll
        for (int r = 0; r < 4; ++r) {
            int rl = mrow + hi*4 + r;
            float m2 = sML[rl*2], l2 = sML[rl*2+1];
            float mm = fmaxf(m[r], m2);
            float f1 = __expf(m[r] - mm), f2 = __expf(m2 - mm);
            float inv = 1.f / (l[r]*f1 + l2*f2);
            int i = q0 + rl;
            #pragma unroll
            for (int dt = 0; dt < 5; ++dt) {
                float val = (acc[dt][r]*f1 + sMrg[rl*80 + dt*16 + lo]*f2) * inv;
                int d = dt*16 + lo;
                if (d < 64)
                    ws_rs[(size_t)i*DH_ + d] = val;
                else if (d - 64 < 12)
                    ws_rp[(size_t)i*12 + (d - 64)] = val;
            }
        }
    }
}

// ---------------------------------------------------------------------------
// K4a: finalize features -> fb[2048][640] bf16. grid = 256, block = 256.
// ---------------------------------------------------------------------------
__global__ __launch_bounds__(256) void k_fin_prep(
    const float* __restrict__ rotations,
    const float* __restrict__ translations,
    const float* __restrict__ ws,
    unsigned short* __restrict__ fb)
{
    __shared__ float sF[8][FDIM];
    const int tid = threadIdx.x;
    const int row0 = blockIdx.x * 8;
    const int b = row0 >> 10;
    const float* ws_rs = ws + OFF_RS;
    const float* ws_rp = ws + OFF_RP;

    for (int i = tid; i < 8*512; i += 256) {
        int r = i >> 9, f = i & 511;
        int h = f >> 6, c = f & 63;
        int n = (row0 & (N_-1)) + r;
        sF[r][f] = ws_rs[(((size_t)(b*H_ + h))*N_ + n)*DH_ + c];
    }
    {
        int r = tid >> 5;
        int idx = tid & 31;
        int h = idx >> 2, pd = idx & 3;
        int row = row0 + r;
        int n = row & (N_-1);
        const float* rp = ws_rp + (((size_t)(b*H_ + h))*N_ + n)*12 + pd*3;
        const float* R = rotations + (size_t)row*9;
        const float* T = translations + (size_t)row*3;
        float d0 = rp[0] - T[0], d1 = rp[1] - T[1], d2 = rp[2] - T[2];
        float l0 = R[0]*d0 + R[3]*d1 + R[6]*d2;
        float l1 = R[1]*d0 + R[4]*d1 + R[7]*d2;
        float l2 = R[2]*d0 + R[5]*d1 + R[8]*d2;
        sF[r][512 + h*12 + pd*3 + 0] = l0;
        sF[r][512 + h*12 + pd*3 + 1] = l1;
        sF[r][512 + h*12 + pd*3 + 2] = l2;
        sF[r][608 + h*4 + pd] = sqrtf(l0*l0 + l1*l1 + l2*l2 + 1e-8f);
    }
    __syncthreads();

    #pragma unroll
    for (int r = 0; r < 8; ++r) {
        for (int f = tid; f < FDIM; f += 256) {
            fb[(size_t)(row0 + r)*FDIM + f] = f2bf(sF[r][f]);
        }
    }
}

// ---------------------------------------------------------------------------
// K4b: output GEMM via MFMA. out[2048][768] = fb . wob^T + bout
// ---------------------------------------------------------------------------
__global__ __launch_bounds__(256) void k_out_mfma(
    const unsigned short* __restrict__ fb,
    const unsigned short* __restrict__ wob,
    const float* __restrict__ bout,
    float* __restrict__ out)
{
    __shared__ unsigned short sAB[2*128*32];
    const int tid  = threadIdx.x;
    const int lane = tid & 63;
    const int wid  = tid >> 6;
    const int mt = blockIdx.x & 15;
    const int nt = blockIdx.x >> 4;
    const int row0 = mt*128;
    const int col0 = nt*128;
    const int wr = (wid >> 1)*64;
    const int wc = (wid & 1)*64;

    f32x4 acc[4][4];
    #pragma unroll
    for (int m = 0; m < 4; ++m)
        #pragma unroll
        for (int n = 0; n < 4; ++n) acc[m][n] = (f32x4){0.f,0.f,0.f,0.f};

    for (int kt = 0; kt < FDIM/32; ++kt) {
        __syncthreads();
        #pragma unroll
        for (int t = 0; t < 4; ++t) {
            int chunk = t*4 + wid;
            int tile  = chunk >> 3;
            int crow  = (chunk & 7) * 16;
            int grow  = (tile ? col0 : row0) + crow + (lane >> 2);
            const unsigned short* gsrc = (tile ? wob : fb)
                + (size_t)grow*FDIM + kt*32 + (lane & 3)*8;
            __builtin_amdgcn_global_load_lds(
                (const __attribute__((address_space(1))) void*)gsrc,
                (__attribute__((address_space(3))) void*)(sAB + chunk*512),
                16, 0, 0);
        }
        __syncthreads();

        bf16x8 a[4], b[4];
        #pragma unroll
        for (int m = 0; m < 4; ++m)
            a[m] = *reinterpret_cast<const bf16x8*>(
                sAB + ((wr + m*16 + (lane & 15))*32 + (lane >> 4)*8));
        #pragma unroll
        for (int n = 0; n < 4; ++n)
            b[n] = *reinterpret_cast<const bf16x8*>(
                sAB + 128*32 + ((wc + n*16 + (lane & 15))*32 + (lane >> 4)*8));
        #pragma unroll
        for (int m = 0; m < 4; ++m)
            #pragma unroll
            for (int n = 0; n < 4; ++n)
                acc[m][n] = __builtin_amdgcn_mfma_f32_16x16x32_bf16(
                    a[m], b[n], acc[m][n], 0, 0, 0);
    }

    #pragma unroll
    for (int n = 0; n < 4; ++n) {
        int o = col0 + wc + n*16 + (lane & 15);
        float bo = bout[o];
        #pragma unroll
        for (int m = 0; m < 4; ++m) {
            #pragma unroll
            for (int j = 0; j < 4; ++j) {
                int r = row0 + wr + m*16 + (lane >> 4)*4 + j;
                out[(size_t)r*DIM_ + o] = acc[m][n][j] + bo;
            }
        }
    }
}

// ---------------------------------------------------------------------------
extern "C" void kernel_launch(void* const* d_in, const int* in_sizes, int n_in,
                              void* d_out, int out_size, void* d_ws, size_t ws_size,
                              hipStream_t stream) {
    const float* x            = (const float*)d_in[0];
    const float* rotations    = (const float*)d_in[1];
    const float* translations = (const float*)d_in[2];
    const float* Wsq          = (const float*)d_in[3];
    const float* Wsk          = (const float*)d_in[4];
    const float* Wsv          = (const float*)d_in[5];
    const float* Wpq          = (const float*)d_in[6];
    const float* Wpk          = (const float*)d_in[7];
    const float* Wpv          = (const float*)d_in[8];
    const float* pweights     = (const float*)d_in[9];
    const float* Wout         = (const float*)d_in[10];
    const float* bout         = (const float*)d_in[11];
    float* out = (float*)d_out;
    float* ws  = (float*)d_ws;

    unsigned short* xb  = (unsigned short*)(ws + OFF_XB);
    unsigned short* wb  = (unsigned short*)(ws + OFF_WB);
    unsigned short* qa  = (unsigned short*)(ws + OFF_QA);
    unsigned short* ka  = (unsigned short*)(ws + OFF_KA);
    unsigned short* vt  = (unsigned short*)(ws + OFF_VT);
    unsigned short* fb  = (unsigned short*)(ws + OFF_FB);
    unsigned short* wob = (unsigned short*)(ws + OFF_WOB);

    k_cvt_x<<<(B_*N_*DIM_/4 + 255)/256, 256, 0, stream>>>(x, xb);
    k_cvt_w<<<(NPAD*DIM_/4 + 255)/256, 256, 0, stream>>>(Wsq, Wsk, Wsv, Wpq, Wpk, Wpv, wb);
    k_proj_mfma<<<16*15, 256, 0, stream>>>(xb, wb, ws);
    k_prep<<<B_*N_, 128, 0, stream>>>(rotations, translations, pweights, ws);
    k_attn_mfma<<<BH_*32, 256, 0, stream>>>(qa, ka, vt, ws);
    // wob overwrites wb region: safe, k_proj_mfma has consumed it (stream order)
    k_cvt_wout<<<(DIM_*FDIM/4 + 255)/256, 256, 0, stream>>>(Wout, wob);
    k_fin_prep<<<B_*N_/8, 256, 0, stream>>>(rotations, translations, ws, fb);
    k_out_mfma<<<16*6, 256, 0, stream>>>(fb, wob, bout, out);
}

// Round 6
// 103.985 us; speedup vs baseline: 1.0836x; 1.0836x over previous
//
#include <hip/hip_runtime.h>
#include <hip/hip_bf16.h>
#include <math.h>

// Problem constants
#define B_  2
#define N_  1024
#define DIM_ 768
#define H_  8
#define DH_ 64
#define PD_ 4
#define NPROJ 1824            // 3*512 + 3*96
#define NPAD  1920            // padded to 15*128
#define BH_ (B_*H_)           // 16
#define FDIM 640              // output feature dim

// ws layout (float offsets)
#define OFF_RS   0u
#define OFF_RP   (OFF_RS + (size_t)BH_*N_*DH_)          // 1048576
#define OFF_PRAW (OFF_RP + (size_t)BH_*N_*12)           // +196608
#define OFF_QA   (OFF_PRAW + (size_t)B_*N_*288)         // +589824 ; bf16 [16][1024][96]
#define OFF_KA   (OFF_QA + (size_t)BH_*N_*96/2)         // +786432
#define OFF_VT   (OFF_KA + (size_t)BH_*N_*96/2)         // bf16 [16][80][1024]
#define OFF_XB   (OFF_VT + (size_t)BH_*80*N_/2)         // bf16 x  (later: fb)
#define OFF_WB   (OFF_XB + (size_t)B_*N_*DIM_/2)        // bf16 packed W (later: wob)
// reuse after projection:
#define OFF_FB   OFF_XB       // bf16 [2048][640]
#define OFF_WOB  OFF_WB       // bf16 [768][640]

typedef __attribute__((ext_vector_type(8))) short bf16x8;
typedef __attribute__((ext_vector_type(4))) float f32x4;

__device__ __forceinline__ float dot4(float4 a, float4 b) {
    return a.x*b.x + a.y*b.y + a.z*b.z + a.w*b.w;
}
__device__ __forceinline__ unsigned short f2bf(float f) {
    __hip_bfloat16 h = __float2bfloat16(f);
    return *reinterpret_cast<unsigned short*>(&h);
}

// ---------------------------------------------------------------------------
// convert x -> bf16
// ---------------------------------------------------------------------------
__global__ __launch_bounds__(256) void k_cvt_x(
    const float* __restrict__ x, unsigned short* __restrict__ xb)
{
    int i = blockIdx.x * 256 + threadIdx.x;
    if (i >= (B_*N_*DIM_)/4) return;
    float4 v = reinterpret_cast<const float4*>(x)[i];
    ushort4 o;
    o.x = f2bf(v.x); o.y = f2bf(v.y); o.z = f2bf(v.z); o.w = f2bf(v.w);
    reinterpret_cast<ushort4*>(xb)[i] = o;
}

// ---------------------------------------------------------------------------
// pack 6 weight mats into wb[1920][768] bf16
// ---------------------------------------------------------------------------
__global__ __launch_bounds__(256) void k_cvt_w(
    const float* __restrict__ Wsq, const float* __restrict__ Wsk,
    const float* __restrict__ Wsv, const float* __restrict__ Wpq,
    const float* __restrict__ Wpk, const float* __restrict__ Wpv,
    unsigned short* __restrict__ wb)
{
    int i = blockIdx.x * 256 + threadIdx.x;
    if (i >= (NPAD*DIM_)/4) return;
    int row = i / (DIM_/4);
    int c4  = i % (DIM_/4);
    ushort4 o;
    if (row >= NPROJ) {
        o.x = o.y = o.z = o.w = 0;
    } else {
        const float* W;
        if      (row < 512)  W = Wsq + (size_t)row*DIM_;
        else if (row < 1024) W = Wsk + (size_t)(row-512)*DIM_;
        else if (row < 1536) W = Wsv + (size_t)(row-1024)*DIM_;
        else if (row < 1632) W = Wpq + (size_t)(row-1536)*DIM_;
        else if (row < 1728) W = Wpk + (size_t)(row-1632)*DIM_;
        else                 W = Wpv + (size_t)(row-1728)*DIM_;
        float4 v = reinterpret_cast<const float4*>(W)[c4];
        o.x = f2bf(v.x); o.y = f2bf(v.y); o.z = f2bf(v.z); o.w = f2bf(v.w);
    }
    reinterpret_cast<ushort4*>(wb)[i] = o;
}

// ---------------------------------------------------------------------------
// convert Wout[768][640] -> bf16
// ---------------------------------------------------------------------------
__global__ __launch_bounds__(256) void k_cvt_wout(
    const float* __restrict__ Wout, unsigned short* __restrict__ wob)
{
    int i = blockIdx.x * 256 + threadIdx.x;
    if (i >= (DIM_*FDIM)/4) return;
    float4 v = reinterpret_cast<const float4*>(Wout)[i];
    ushort4 o;
    o.x = f2bf(v.x); o.y = f2bf(v.y); o.z = f2bf(v.z); o.w = f2bf(v.w);
    reinterpret_cast<ushort4*>(wob)[i] = o;
}

// ---------------------------------------------------------------------------
// K1: projection GEMM via MFMA; epilogue writes Qa/Ka/Vt (bf16) + praw (f32)
// ---------------------------------------------------------------------------
__global__ __launch_bounds__(256) void k_proj_mfma(
    const unsigned short* __restrict__ xb,
    const unsigned short* __restrict__ wb,
    float* __restrict__ ws)
{
    __shared__ unsigned short sAB[2*128*32];
    const int tid  = threadIdx.x;
    const int lane = tid & 63;
    const int wid  = tid >> 6;
    const int mt = blockIdx.x & 15;
    const int nt = blockIdx.x >> 4;
    const int row0 = mt*128;
    const int col0 = nt*128;
    const int wr = (wid >> 1)*64;
    const int wc = (wid & 1)*64;

    f32x4 acc[4][4];
    #pragma unroll
    for (int m = 0; m < 4; ++m)
        #pragma unroll
        for (int n = 0; n < 4; ++n) acc[m][n] = (f32x4){0.f,0.f,0.f,0.f};

    for (int kt = 0; kt < DIM_/32; ++kt) {
        __syncthreads();
        #pragma unroll
        for (int t = 0; t < 4; ++t) {
            int chunk = t*4 + wid;
            int tile  = chunk >> 3;
            int crow  = (chunk & 7) * 16;
            int grow  = (tile ? col0 : row0) + crow + (lane >> 2);
            const unsigned short* gsrc = (tile ? wb : xb)
                + (size_t)grow*DIM_ + kt*32 + (lane & 3)*8;
            __builtin_amdgcn_global_load_lds(
                (const __attribute__((address_space(1))) void*)gsrc,
                (__attribute__((address_space(3))) void*)(sAB + chunk*512),
                16, 0, 0);
        }
        __syncthreads();

        bf16x8 a[4], b[4];
        #pragma unroll
        for (int m = 0; m < 4; ++m)
            a[m] = *reinterpret_cast<const bf16x8*>(
                sAB + ((wr + m*16 + (lane & 15))*32 + (lane >> 4)*8));
        #pragma unroll
        for (int n = 0; n < 4; ++n)
            b[n] = *reinterpret_cast<const bf16x8*>(
                sAB + 128*32 + ((wc + n*16 + (lane & 15))*32 + (lane >> 4)*8));
        #pragma unroll
        for (int m = 0; m < 4; ++m)
            #pragma unroll
            for (int n = 0; n < 4; ++n)
                acc[m][n] = __builtin_amdgcn_mfma_f32_16x16x32_bf16(
                    a[m], b[n], acc[m][n], 0, 0, 0);
    }

    unsigned short* qa = (unsigned short*)(ws + OFF_QA);
    unsigned short* ka = (unsigned short*)(ws + OFF_KA);
    unsigned short* vt = (unsigned short*)(ws + OFF_VT);
    float* praw = ws + OFF_PRAW;
    const float ss = 0.08838834764831845f;   // (2*64)^-0.5

    #pragma unroll
    for (int n = 0; n < 4; ++n) {
        int o = col0 + wc + n*16 + (lane & 15);
        if (o >= NPROJ) continue;
        #pragma unroll
        for (int m = 0; m < 4; ++m) {
            #pragma unroll
            for (int j = 0; j < 4; ++j) {
                int r = row0 + wr + m*16 + (lane >> 4)*4 + j;
                int bb = r >> 10, nn = r & (N_-1);
                float v = acc[m][n][j];
                if (o < 512) {
                    int h = o >> 6, c = o & 63;
                    qa[((size_t)(bb*H_ + h)*N_ + nn)*96 + c] = f2bf(v*ss);
                } else if (o < 1024) {
                    int oo = o - 512; int h = oo >> 6, c = oo & 63;
                    ka[((size_t)(bb*H_ + h)*N_ + nn)*96 + c] = f2bf(v);
                } else if (o < 1536) {
                    int oo = o - 1024; int h = oo >> 6, c = oo & 63;
                    vt[((size_t)(bb*H_ + h)*80 + c)*N_ + nn] = f2bf(v);
                } else {
                    praw[(size_t)r*288 + (o - 1536)] = v;
                }
            }
        }
    }
}

// ---------------------------------------------------------------------------
// K2: rotate points, q2/k2, write Qa/Ka tails + Vt point rows (+ zero pads)
// ---------------------------------------------------------------------------
__global__ __launch_bounds__(128) void k_prep(
    const float* __restrict__ rot_g,
    const float* __restrict__ trans_g,
    const float* __restrict__ pw_g,
    float* __restrict__ ws)
{
    __shared__ float R[9], T[3];
    __shared__ float rot[3][8][4][3];
    __shared__ float p2[2][8][4];
    __shared__ float q2t[8], k2t[8], coefs[8];
    const int tid = threadIdx.x;
    const int row = blockIdx.x;
    const int b = row >> 10, n = row & (N_-1);

    if (tid < 9)  R[tid] = rot_g[(size_t)row*9 + tid];
    if (tid >= 9 && tid < 12) T[tid-9] = trans_g[(size_t)row*3 + (tid-9)];
    if (tid >= 16 && tid < 24) {
        float pw = pw_g[tid-16];
        coefs[tid-16] = 0.5f * log1pf(__expf(pw)) * (1.0f/6.0f);
    }
    __syncthreads();
    if (tid < 96) {
        int which = tid >> 5, idx = tid & 31;
        int h = idx >> 2, pd = idx & 3;
        const float* p = ws + OFF_PRAW + (size_t)row*288 + which*96 + h*12 + pd*3;
        float px = p[0], py = p[1], pz = p[2];
        float c0 = R[0]*px + R[1]*py + R[2]*pz + T[0];
        float c1 = R[3]*px + R[4]*py + R[5]*pz + T[1];
        float c2 = R[6]*px + R[7]*py + R[8]*pz + T[2];
        rot[which][h][pd][0] = c0;
        rot[which][h][pd][1] = c1;
        rot[which][h][pd][2] = c2;
        if (which < 2) p2[which][h][pd] = c0*c0 + c1*c1 + c2*c2;
    }
    __syncthreads();
    if (tid < 16) {
        int w = tid >> 3, h = tid & 7;
        float s = p2[w][h][0] + p2[w][h][1] + p2[w][h][2] + p2[w][h][3];
        if (w) k2t[h] = s; else q2t[h] = s;
    }
    __syncthreads();

    unsigned short* qa = (unsigned short*)(ws + OFF_QA);
    unsigned short* ka = (unsigned short*)(ws + OFF_KA);
    unsigned short* vt = (unsigned short*)(ws + OFF_VT);

    for (int i = tid; i < 256; i += 128) {
        int h = i >> 5, c = i & 31;
        float qv, kv;
        if (c < 12)      { qv = rot[0][h][c/3][c%3] * 2.f * coefs[h]; kv = rot[1][h][c/3][c%3]; }
        else if (c == 12){ qv = q2t[h];  kv = -coefs[h]; }
        else if (c == 13){ qv = 1.f;     kv = -coefs[h]*k2t[h]; }
        else             { qv = 0.f;     kv = 0.f; }
        size_t base = ((size_t)(b*H_ + h)*N_ + n)*96 + 64 + c;
        qa[base] = f2bf(qv);
        ka[base] = f2bf(kv);
    }
    {
        int h = tid >> 4, r = tid & 15;
        float vv = (r < 12) ? rot[2][h][r/3][r%3] : 0.f;
        vt[((size_t)(b*H_ + h)*80 + 64 + r)*N_ + n] = f2bf(vv);
    }
}

// ---------------------------------------------------------------------------
// K3: MFMA flash attention, direct-global K/V, 8 waves, k-split 4, XCD swizzle.
// grid = 512 blocks x 512 threads.
// wave w: qhalf = w&1 (16 rows), kquarter = w>>2? no: w>>1 (4 tiles of 64 keys)
// ---------------------------------------------------------------------------
#define VPAD 72
#define APAD 84
__global__ __launch_bounds__(512) void k_attn_mfma(
    const unsigned short* __restrict__ qa_g,
    const unsigned short* __restrict__ ka_g,
    const unsigned short* __restrict__ vt_g,
    float* __restrict__ ws)
{
    __shared__ unsigned short sP[8][16*VPAD];
    __shared__ float sAcc[3][2][16][APAD];
    __shared__ float sML[3][2][16][2];

    const int tid  = threadIdx.x;
    const int lane = tid & 63;
    const int wid  = tid >> 6;          // 0..7
    const int lo = lane & 15;
    const int hi = lane >> 4;
    // XCD-aware swizzle: 512 blocks, 8 XCDs, 64 blocks/XCD chunk
    const int bid = blockIdx.x;
    const int Lb = (bid & 7)*64 + (bid >> 3);
    const int bh = Lb >> 5;
    const int qt = Lb & 31;
    const int q0 = qt * 32;
    const int qh = wid & 1;             // which 16-row half of the q-tile
    const int kq = wid >> 1;            // 0..3, key quarter
    const int mrow = qh * 16;

    const unsigned short* Qa = qa_g + (size_t)bh*N_*96;
    const unsigned short* Ka = ka_g + (size_t)bh*N_*96;
    const unsigned short* Vt = vt_g + (size_t)bh*80*N_;

    bf16x8 qfr[3];
    {
        int qrow = q0 + mrow + lo;
        #pragma unroll
        for (int c = 0; c < 3; ++c)
            qfr[c] = *reinterpret_cast<const bf16x8*>(
                Qa + (size_t)qrow*96 + c*32 + hi*8);
    }

    f32x4 acc[5];
    #pragma unroll
    for (int d = 0; d < 5; ++d) acc[d] = (f32x4){0.f,0.f,0.f,0.f};
    float m[4] = {-1e30f,-1e30f,-1e30f,-1e30f};
    float l[4] = {0.f,0.f,0.f,0.f};

    #pragma unroll 2
    for (int it = 0; it < 4; ++it) {
        const int j0 = (kq*4 + it)*64;

        // S = Qa . Ka^T  — K fragments straight from global (L2)
        f32x4 s[4];
        #pragma unroll
        for (int t = 0; t < 4; ++t) s[t] = (f32x4){0.f,0.f,0.f,0.f};
        #pragma unroll
        for (int c = 0; c < 3; ++c) {
            bf16x8 kb[4];
            #pragma unroll
            for (int t = 0; t < 4; ++t)
                kb[t] = *reinterpret_cast<const bf16x8*>(
                    Ka + (size_t)(j0 + t*16 + lo)*96 + c*32 + hi*8);
            #pragma unroll
            for (int t = 0; t < 4; ++t)
                s[t] = __builtin_amdgcn_mfma_f32_16x16x32_bf16(qfr[c], kb[t], s[t], 0, 0, 0);
        }

        // online softmax; rows r: i = hi*4 + r, cols j = t*16 + lo
        float scl[4];
        #pragma unroll
        for (int r = 0; r < 4; ++r) {
            float v = fmaxf(fmaxf(s[0][r], s[1][r]), fmaxf(s[2][r], s[3][r]));
            v = fmaxf(v, __shfl_xor(v, 1));
            v = fmaxf(v, __shfl_xor(v, 2));
            v = fmaxf(v, __shfl_xor(v, 4));
            v = fmaxf(v, __shfl_xor(v, 8));
            float mn = fmaxf(m[r], v);
            scl[r] = __expf(m[r] - mn);
            m[r] = mn;
        }
        float ps[4] = {0.f,0.f,0.f,0.f};
        #pragma unroll
        for (int t = 0; t < 4; ++t) {
            #pragma unroll
            for (int r = 0; r < 4; ++r) {
                float p = __expf(s[t][r] - m[r]);
                ps[r] += p;
                sP[wid][(hi*4 + r)*VPAD + t*16 + lo] = f2bf(p);
            }
        }
        #pragma unroll
        for (int r = 0; r < 4; ++r) {
            float v = ps[r];
            v += __shfl_xor(v, 1);
            v += __shfl_xor(v, 2);
            v += __shfl_xor(v, 4);
            v += __shfl_xor(v, 8);
            l[r] = l[r]*scl[r] + v;
        }
        #pragma unroll
        for (int d = 0; d < 5; ++d)
            #pragma unroll
            for (int r = 0; r < 4; ++r) acc[d][r] *= scl[r];

        // PV: O += P . V — V fragments straight from global (L2)
        #pragma unroll
        for (int kk = 0; kk < 2; ++kk) {
            bf16x8 pa = *reinterpret_cast<const bf16x8*>(
                &sP[wid][lo*VPAD + kk*32 + hi*8]);
            #pragma unroll
            for (int dt = 0; dt < 5; ++dt) {
                bf16x8 vb = *reinterpret_cast<const bf16x8*>(
                    Vt + (size_t)(dt*16 + lo)*N_ + j0 + kk*32 + hi*8);
                acc[dt] = __builtin_amdgcn_mfma_f32_16x16x32_bf16(pa, vb, acc[dt], 0, 0, 0);
            }
        }
    }

    // 4-way k-split merge through LDS
    if (kq > 0) {
        #pragma unroll
        for (int r = 0; r < 4; ++r) {
            int rl = hi*4 + r;
            #pragma unroll
            for (int dt = 0; dt < 5; ++dt)
                sAcc[kq-1][qh][rl][dt*16 + lo] = acc[dt][r];
            if (lo == 0) { sML[kq-1][qh][rl][0] = m[r]; sML[kq-1][qh][rl][1] = l[r]; }
        }
    }
    __syncthreads();
    if (kq == 0) {
        float* ws_rs = ws + OFF_RS + (size_t)bh*N_*DH_;
        float* ws_rp = ws + OFF_RP + (size_t)bh*N_*12;
        #pragma unroll
        for (int r = 0; r < 4; ++r) {
            int rl = hi*4 + r;
            float mp[3], lp[3];
            float mm = m[r];
            #pragma unroll
            for (int p = 0; p < 3; ++p) {
                mp[p] = sML[p][qh][rl][0];
                lp[p] = sML[p][qh][rl][1];
                mm = fmaxf(mm, mp[p]);
            }
            float f0 = __expf(m[r] - mm);
            float Lsum = l[r]*f0;
            float fp[3];
            #pragma unroll
            for (int p = 0; p < 3; ++p) {
                fp[p] = __expf(mp[p] - mm);
                Lsum += lp[p]*fp[p];
            }
            float inv = 1.f / Lsum;
            int i = q0 + mrow + rl;
            #pragma unroll
            for (int dt = 0; dt < 5; ++dt) {
                float val = acc[dt][r]*f0;
                #pragma unroll
                for (int p = 0; p < 3; ++p)
                    val += sAcc[p][qh][rl][dt*16 + lo]*fp[p];
                val *= inv;
                int d = dt*16 + lo;
                if (d < 64)
                    ws_rs[(size_t)i*DH_ + d] = val;
                else if (d - 64 < 12)
                    ws_rp[(size_t)i*12 + (d - 64)] = val;
            }
        }
    }
}

// ---------------------------------------------------------------------------
// K4a: finalize features -> fb[2048][640] bf16. grid = 256, block = 256.
// ---------------------------------------------------------------------------
__global__ __launch_bounds__(256) void k_fin_prep(
    const float* __restrict__ rotations,
    const float* __restrict__ translations,
    const float* __restrict__ ws,
    unsigned short* __restrict__ fb)
{
    __shared__ float sF[8][FDIM];
    const int tid = threadIdx.x;
    const int row0 = blockIdx.x * 8;
    const int b = row0 >> 10;
    const float* ws_rs = ws + OFF_RS;
    const float* ws_rp = ws + OFF_RP;

    for (int i = tid; i < 8*512; i += 256) {
        int r = i >> 9, f = i & 511;
        int h = f >> 6, c = f & 63;
        int n = (row0 & (N_-1)) + r;
        sF[r][f] = ws_rs[(((size_t)(b*H_ + h))*N_ + n)*DH_ + c];
    }
    {
        int r = tid >> 5;
        int idx = tid & 31;
        int h = idx >> 2, pd = idx & 3;
        int row = row0 + r;
        int n = row & (N_-1);
        const float* rp = ws_rp + (((size_t)(b*H_ + h))*N_ + n)*12 + pd*3;
        const float* R = rotations + (size_t)row*9;
        const float* T = translations + (size_t)row*3;
        float d0 = rp[0] - T[0], d1 = rp[1] - T[1], d2 = rp[2] - T[2];
        float l0 = R[0]*d0 + R[3]*d1 + R[6]*d2;
        float l1 = R[1]*d0 + R[4]*d1 + R[7]*d2;
        float l2 = R[2]*d0 + R[5]*d1 + R[8]*d2;
        sF[r][512 + h*12 + pd*3 + 0] = l0;
        sF[r][512 + h*12 + pd*3 + 1] = l1;
        sF[r][512 + h*12 + pd*3 + 2] = l2;
        sF[r][608 + h*4 + pd] = sqrtf(l0*l0 + l1*l1 + l2*l2 + 1e-8f);
    }
    __syncthreads();

    #pragma unroll
    for (int r = 0; r < 8; ++r) {
        for (int f = tid; f < FDIM; f += 256) {
            fb[(size_t)(row0 + r)*FDIM + f] = f2bf(sF[r][f]);
        }
    }
}

// ---------------------------------------------------------------------------
// K4b: output GEMM via MFMA. out[2048][768] = fb . wob^T + bout
// ---------------------------------------------------------------------------
__global__ __launch_bounds__(256) void k_out_mfma(
    const unsigned short* __restrict__ fb,
    const unsigned short* __restrict__ wob,
    const float* __restrict__ bout,
    float* __restrict__ out)
{
    __shared__ unsigned short sAB[2*128*32];
    const int tid  = threadIdx.x;
    const int lane = tid & 63;
    const int wid  = tid >> 6;
    const int mt = blockIdx.x & 15;
    const int nt = blockIdx.x >> 4;
    const int row0 = mt*128;
    const int col0 = nt*128;
    const int wr = (wid >> 1)*64;
    const int wc = (wid & 1)*64;

    f32x4 acc[4][4];
    #pragma unroll
    for (int m = 0; m < 4; ++m)
        #pragma unroll
        for (int n = 0; n < 4; ++n) acc[m][n] = (f32x4){0.f,0.f,0.f,0.f};

    for (int kt = 0; kt < FDIM/32; ++kt) {
        __syncthreads();
        #pragma unroll
        for (int t = 0; t < 4; ++t) {
            int chunk = t*4 + wid;
            int tile  = chunk >> 3;
            int crow  = (chunk & 7) * 16;
            int grow  = (tile ? col0 : row0) + crow + (lane >> 2);
            const unsigned short* gsrc = (tile ? wob : fb)
                + (size_t)grow*FDIM + kt*32 + (lane & 3)*8;
            __builtin_amdgcn_global_load_lds(
                (const __attribute__((address_space(1))) void*)gsrc,
                (__attribute__((address_space(3))) void*)(sAB + chunk*512),
                16, 0, 0);
        }
        __syncthreads();

        bf16x8 a[4], b[4];
        #pragma unroll
        for (int m = 0; m < 4; ++m)
            a[m] = *reinterpret_cast<const bf16x8*>(
                sAB + ((wr + m*16 + (lane & 15))*32 + (lane >> 4)*8));
        #pragma unroll
        for (int n = 0; n < 4; ++n)
            b[n] = *reinterpret_cast<const bf16x8*>(
                sAB + 128*32 + ((wc + n*16 + (lane & 15))*32 + (lane >> 4)*8));
        #pragma unroll
        for (int m = 0; m < 4; ++m)
            #pragma unroll
            for (int n = 0; n < 4; ++n)
                acc[m][n] = __builtin_amdgcn_mfma_f32_16x16x32_bf16(
                    a[m], b[n], acc[m][n], 0, 0, 0);
    }

    #pragma unroll
    for (int n = 0; n < 4; ++n) {
        int o = col0 + wc + n*16 + (lane & 15);
        float bo = bout[o];
        #pragma unroll
        for (int m = 0; m < 4; ++m) {
            #pragma unroll
            for (int j = 0; j < 4; ++j) {
                int r = row0 + wr + m*16 + (lane >> 4)*4 + j;
                out[(size_t)r*DIM_ + o] = acc[m][n][j] + bo;
            }
        }
    }
}

// ---------------------------------------------------------------------------
extern "C" void kernel_launch(void* const* d_in, const int* in_sizes, int n_in,
                              void* d_out, int out_size, void* d_ws, size_t ws_size,
                              hipStream_t stream) {
    const float* x            = (const float*)d_in[0];
    const float* rotations    = (const float*)d_in[1];
    const float* translations = (const float*)d_in[2];
    const float* Wsq          = (const float*)d_in[3];
    const float* Wsk          = (const float*)d_in[4];
    const float* Wsv          = (const float*)d_in[5];
    const float* Wpq          = (const float*)d_in[6];
    const float* Wpk          = (const float*)d_in[7];
    const float* Wpv          = (const float*)d_in[8];
    const float* pweights     = (const float*)d_in[9];
    const float* Wout         = (const float*)d_in[10];
    const float* bout         = (const float*)d_in[11];
    float* out = (float*)d_out;
    float* ws  = (float*)d_ws;

    unsigned short* xb  = (unsigned short*)(ws + OFF_XB);
    unsigned short* wb  = (unsigned short*)(ws + OFF_WB);
    unsigned short* qa  = (unsigned short*)(ws + OFF_QA);
    unsigned short* ka  = (unsigned short*)(ws + OFF_KA);
    unsigned short* vt  = (unsigned short*)(ws + OFF_VT);
    unsigned short* fb  = (unsigned short*)(ws + OFF_FB);
    unsigned short* wob = (unsigned short*)(ws + OFF_WOB);

    k_cvt_x<<<(B_*N_*DIM_/4 + 255)/256, 256, 0, stream>>>(x, xb);
    k_cvt_w<<<(NPAD*DIM_/4 + 255)/256, 256, 0, stream>>>(Wsq, Wsk, Wsv, Wpq, Wpk, Wpv, wb);
    k_proj_mfma<<<16*15, 256, 0, stream>>>(xb, wb, ws);
    k_prep<<<B_*N_, 128, 0, stream>>>(rotations, translations, pweights, ws);
    k_attn_mfma<<<BH_*32, 512, 0, stream>>>(qa, ka, vt, ws);
    // wob overwrites wb region: safe, k_proj_mfma has consumed it (stream order)
    k_cvt_wout<<<(DIM_*FDIM/4 + 255)/256, 256, 0, stream>>>(Wout, wob);
    k_fin_prep<<<B_*N_/8, 256, 0, stream>>>(rotations, translations, ws, fb);
    k_out_mfma<<<16*6, 256, 0, stream>>>(fb, wob, bout, out);
}

// Round 7
// 100.910 us; speedup vs baseline: 1.1166x; 1.0305x over previous
//
#include <hip/hip_runtime.h>
#include <hip/hip_bf16.h>
#include <math.h>

// Problem constants
#define B_  2
#define N_  1024
#define DIM_ 768
#define H_  8
#define DH_ 64
#define PD_ 4
#define NPROJ 1824            // 3*512 + 3*96
#define NPAD  1920            // padded to 15*128
#define BH_ (B_*H_)           // 16
#define FDIM 640              // output feature dim

// ws layout (float offsets)
#define OFF_RS   0u
#define OFF_RP   (OFF_RS + (size_t)BH_*N_*DH_)          // 1048576
#define OFF_PRAW (OFF_RP + (size_t)BH_*N_*12)           // +196608
#define OFF_QA   (OFF_PRAW + (size_t)B_*N_*288)         // +589824 ; bf16 [16][1024][96]
#define OFF_KA   (OFF_QA + (size_t)BH_*N_*96/2)         // +786432
#define OFF_VT   (OFF_KA + (size_t)BH_*N_*96/2)         // bf16 [16][80][1024]
#define OFF_XB   (OFF_VT + (size_t)BH_*80*N_/2)         // bf16 x  (later: fb)
#define OFF_WB   (OFF_XB + (size_t)B_*N_*DIM_/2)        // bf16 packed W (later: wob)
// reuse after projection:
#define OFF_FB   OFF_XB       // bf16 [2048][640]
#define OFF_WOB  OFF_WB       // bf16 [768][640]

typedef __attribute__((ext_vector_type(8))) short bf16x8;
typedef __attribute__((ext_vector_type(4))) float f32x4;

__device__ __forceinline__ float dot4(float4 a, float4 b) {
    return a.x*b.x + a.y*b.y + a.z*b.z + a.w*b.w;
}
__device__ __forceinline__ unsigned short f2bf(float f) {
    __hip_bfloat16 h = __float2bfloat16(f);
    return *reinterpret_cast<unsigned short*>(&h);
}

// ---------------------------------------------------------------------------
// convert x -> bf16
// ---------------------------------------------------------------------------
__global__ __launch_bounds__(256) void k_cvt_x(
    const float* __restrict__ x, unsigned short* __restrict__ xb)
{
    int i = blockIdx.x * 256 + threadIdx.x;
    if (i >= (B_*N_*DIM_)/4) return;
    float4 v = reinterpret_cast<const float4*>(x)[i];
    ushort4 o;
    o.x = f2bf(v.x); o.y = f2bf(v.y); o.z = f2bf(v.z); o.w = f2bf(v.w);
    reinterpret_cast<ushort4*>(xb)[i] = o;
}

// ---------------------------------------------------------------------------
// pack 6 weight mats into wb[1920][768] bf16
// ---------------------------------------------------------------------------
__global__ __launch_bounds__(256) void k_cvt_w(
    const float* __restrict__ Wsq, const float* __restrict__ Wsk,
    const float* __restrict__ Wsv, const float* __restrict__ Wpq,
    const float* __restrict__ Wpk, const float* __restrict__ Wpv,
    unsigned short* __restrict__ wb)
{
    int i = blockIdx.x * 256 + threadIdx.x;
    if (i >= (NPAD*DIM_)/4) return;
    int row = i / (DIM_/4);
    int c4  = i % (DIM_/4);
    ushort4 o;
    if (row >= NPROJ) {
        o.x = o.y = o.z = o.w = 0;
    } else {
        const float* W;
        if      (row < 512)  W = Wsq + (size_t)row*DIM_;
        else if (row < 1024) W = Wsk + (size_t)(row-512)*DIM_;
        else if (row < 1536) W = Wsv + (size_t)(row-1024)*DIM_;
        else if (row < 1632) W = Wpq + (size_t)(row-1536)*DIM_;
        else if (row < 1728) W = Wpk + (size_t)(row-1632)*DIM_;
        else                 W = Wpv + (size_t)(row-1728)*DIM_;
        float4 v = reinterpret_cast<const float4*>(W)[c4];
        o.x = f2bf(v.x); o.y = f2bf(v.y); o.z = f2bf(v.z); o.w = f2bf(v.w);
    }
    reinterpret_cast<ushort4*>(wb)[i] = o;
}

// ---------------------------------------------------------------------------
// convert Wout[768][640] -> bf16
// ---------------------------------------------------------------------------
__global__ __launch_bounds__(256) void k_cvt_wout(
    const float* __restrict__ Wout, unsigned short* __restrict__ wob)
{
    int i = blockIdx.x * 256 + threadIdx.x;
    if (i >= (DIM_*FDIM)/4) return;
    float4 v = reinterpret_cast<const float4*>(Wout)[i];
    ushort4 o;
    o.x = f2bf(v.x); o.y = f2bf(v.y); o.z = f2bf(v.z); o.w = f2bf(v.w);
    reinterpret_cast<ushort4*>(wob)[i] = o;
}

// ---------------------------------------------------------------------------
// K1: projection GEMM via MFMA; epilogue writes Qa/Ka/Vt (bf16) + praw (f32)
// ---------------------------------------------------------------------------
__global__ __launch_bounds__(256) void k_proj_mfma(
    const unsigned short* __restrict__ xb,
    const unsigned short* __restrict__ wb,
    float* __restrict__ ws)
{
    __shared__ unsigned short sAB[2*128*32];
    const int tid  = threadIdx.x;
    const int lane = tid & 63;
    const int wid  = tid >> 6;
    const int mt = blockIdx.x & 15;
    const int nt = blockIdx.x >> 4;
    const int row0 = mt*128;
    const int col0 = nt*128;
    const int wr = (wid >> 1)*64;
    const int wc = (wid & 1)*64;

    f32x4 acc[4][4];
    #pragma unroll
    for (int m = 0; m < 4; ++m)
        #pragma unroll
        for (int n = 0; n < 4; ++n) acc[m][n] = (f32x4){0.f,0.f,0.f,0.f};

    for (int kt = 0; kt < DIM_/32; ++kt) {
        __syncthreads();
        #pragma unroll
        for (int t = 0; t < 4; ++t) {
            int chunk = t*4 + wid;
            int tile  = chunk >> 3;
            int crow  = (chunk & 7) * 16;
            int grow  = (tile ? col0 : row0) + crow + (lane >> 2);
            const unsigned short* gsrc = (tile ? wb : xb)
                + (size_t)grow*DIM_ + kt*32 + (lane & 3)*8;
            __builtin_amdgcn_global_load_lds(
                (const __attribute__((address_space(1))) void*)gsrc,
                (__attribute__((address_space(3))) void*)(sAB + chunk*512),
                16, 0, 0);
        }
        __syncthreads();

        bf16x8 a[4], b[4];
        #pragma unroll
        for (int m = 0; m < 4; ++m)
            a[m] = *reinterpret_cast<const bf16x8*>(
                sAB + ((wr + m*16 + (lane & 15))*32 + (lane >> 4)*8));
        #pragma unroll
        for (int n = 0; n < 4; ++n)
            b[n] = *reinterpret_cast<const bf16x8*>(
                sAB + 128*32 + ((wc + n*16 + (lane & 15))*32 + (lane >> 4)*8));
        #pragma unroll
        for (int m = 0; m < 4; ++m)
            #pragma unroll
            for (int n = 0; n < 4; ++n)
                acc[m][n] = __builtin_amdgcn_mfma_f32_16x16x32_bf16(
                    a[m], b[n], acc[m][n], 0, 0, 0);
    }

    unsigned short* qa = (unsigned short*)(ws + OFF_QA);
    unsigned short* ka = (unsigned short*)(ws + OFF_KA);
    unsigned short* vt = (unsigned short*)(ws + OFF_VT);
    float* praw = ws + OFF_PRAW;
    const float ss = 0.08838834764831845f;   // (2*64)^-0.5

    #pragma unroll
    for (int n = 0; n < 4; ++n) {
        int o = col0 + wc + n*16 + (lane & 15);
        if (o >= NPROJ) continue;
        #pragma unroll
        for (int m = 0; m < 4; ++m) {
            #pragma unroll
            for (int j = 0; j < 4; ++j) {
                int r = row0 + wr + m*16 + (lane >> 4)*4 + j;
                int bb = r >> 10, nn = r & (N_-1);
                float v = acc[m][n][j];
                if (o < 512) {
                    int h = o >> 6, c = o & 63;
                    qa[((size_t)(bb*H_ + h)*N_ + nn)*96 + c] = f2bf(v*ss);
                } else if (o < 1024) {
                    int oo = o - 512; int h = oo >> 6, c = oo & 63;
                    ka[((size_t)(bb*H_ + h)*N_ + nn)*96 + c] = f2bf(v);
                } else if (o < 1536) {
                    int oo = o - 1024; int h = oo >> 6, c = oo & 63;
                    vt[((size_t)(bb*H_ + h)*80 + c)*N_ + nn] = f2bf(v);
                } else {
                    praw[(size_t)r*288 + (o - 1536)] = v;
                }
            }
        }
    }
}

// ---------------------------------------------------------------------------
// K2: rotate points, q2/k2, write Qa/Ka tails + Vt point rows (+ zero pads)
// ---------------------------------------------------------------------------
__global__ __launch_bounds__(128) void k_prep(
    const float* __restrict__ rot_g,
    const float* __restrict__ trans_g,
    const float* __restrict__ pw_g,
    float* __restrict__ ws)
{
    __shared__ float R[9], T[3];
    __shared__ float rot[3][8][4][3];
    __shared__ float p2[2][8][4];
    __shared__ float q2t[8], k2t[8], coefs[8];
    const int tid = threadIdx.x;
    const int row = blockIdx.x;
    const int b = row >> 10, n = row & (N_-1);

    if (tid < 9)  R[tid] = rot_g[(size_t)row*9 + tid];
    if (tid >= 9 && tid < 12) T[tid-9] = trans_g[(size_t)row*3 + (tid-9)];
    if (tid >= 16 && tid < 24) {
        float pw = pw_g[tid-16];
        coefs[tid-16] = 0.5f * log1pf(__expf(pw)) * (1.0f/6.0f);
    }
    __syncthreads();
    if (tid < 96) {
        int which = tid >> 5, idx = tid & 31;
        int h = idx >> 2, pd = idx & 3;
        const float* p = ws + OFF_PRAW + (size_t)row*288 + which*96 + h*12 + pd*3;
        float px = p[0], py = p[1], pz = p[2];
        float c0 = R[0]*px + R[1]*py + R[2]*pz + T[0];
        float c1 = R[3]*px + R[4]*py + R[5]*pz + T[1];
        float c2 = R[6]*px + R[7]*py + R[8]*pz + T[2];
        rot[which][h][pd][0] = c0;
        rot[which][h][pd][1] = c1;
        rot[which][h][pd][2] = c2;
        if (which < 2) p2[which][h][pd] = c0*c0 + c1*c1 + c2*c2;
    }
    __syncthreads();
    if (tid < 16) {
        int w = tid >> 3, h = tid & 7;
        float s = p2[w][h][0] + p2[w][h][1] + p2[w][h][2] + p2[w][h][3];
        if (w) k2t[h] = s; else q2t[h] = s;
    }
    __syncthreads();

    unsigned short* qa = (unsigned short*)(ws + OFF_QA);
    unsigned short* ka = (unsigned short*)(ws + OFF_KA);
    unsigned short* vt = (unsigned short*)(ws + OFF_VT);

    for (int i = tid; i < 256; i += 128) {
        int h = i >> 5, c = i & 31;
        float qv, kv;
        if (c < 12)      { qv = rot[0][h][c/3][c%3] * 2.f * coefs[h]; kv = rot[1][h][c/3][c%3]; }
        else if (c == 12){ qv = q2t[h];  kv = -coefs[h]; }
        else if (c == 13){ qv = 1.f;     kv = -coefs[h]*k2t[h]; }
        else             { qv = 0.f;     kv = 0.f; }
        size_t base = ((size_t)(b*H_ + h)*N_ + n)*96 + 64 + c;
        qa[base] = f2bf(qv);
        ka[base] = f2bf(kv);
    }
    {
        int h = tid >> 4, r = tid & 15;
        float vv = (r < 12) ? rot[2][h][r/3][r%3] : 0.f;
        vt[((size_t)(b*H_ + h)*80 + 64 + r)*N_ + n] = f2bf(vv);
    }
}

// ---------------------------------------------------------------------------
// K3: MFMA flash attention, direct-global K/V, 8 waves, k-split 4, XCD swizzle.
// Batched fragment loads (128-VGPR budget) to minimize exposed L2 latency.
// grid = 512 blocks x 512 threads.
// ---------------------------------------------------------------------------
#define VPAD 72
#define APAD 84
__global__ __launch_bounds__(512, 4) void k_attn_mfma(
    const unsigned short* __restrict__ qa_g,
    const unsigned short* __restrict__ ka_g,
    const unsigned short* __restrict__ vt_g,
    float* __restrict__ ws)
{
    __shared__ unsigned short sP[8][16*VPAD];
    __shared__ float sAcc[3][2][16][APAD];
    __shared__ float sML[3][2][16][2];

    const int tid  = threadIdx.x;
    const int lane = tid & 63;
    const int wid  = tid >> 6;          // 0..7
    const int lo = lane & 15;
    const int hi = lane >> 4;
    // XCD-aware swizzle: 512 blocks, 8 XCDs, 64 blocks/XCD chunk
    const int bid = blockIdx.x;
    const int Lb = (bid & 7)*64 + (bid >> 3);
    const int bh = Lb >> 5;
    const int qt = Lb & 31;
    const int q0 = qt * 32;
    const int qh = wid & 1;             // which 16-row half of the q-tile
    const int kq = wid >> 1;            // 0..3, key quarter
    const int mrow = qh * 16;

    const unsigned short* Qa = qa_g + (size_t)bh*N_*96;
    const unsigned short* Ka = ka_g + (size_t)bh*N_*96;
    const unsigned short* Vt = vt_g + (size_t)bh*80*N_;

    bf16x8 qfr[3];
    {
        int qrow = q0 + mrow + lo;
        #pragma unroll
        for (int c = 0; c < 3; ++c)
            qfr[c] = *reinterpret_cast<const bf16x8*>(
                Qa + (size_t)qrow*96 + c*32 + hi*8);
    }

    f32x4 acc[5];
    #pragma unroll
    for (int d = 0; d < 5; ++d) acc[d] = (f32x4){0.f,0.f,0.f,0.f};
    float m[4] = {-1e30f,-1e30f,-1e30f,-1e30f};
    float l[4] = {0.f,0.f,0.f,0.f};

    for (int it = 0; it < 4; ++it) {
        const int j0 = (kq*4 + it)*64;

        // --- issue ALL 12 K-fragment loads (batched, one wait) ---
        bf16x8 kb[3][4];
        #pragma unroll
        for (int c = 0; c < 3; ++c)
            #pragma unroll
            for (int t = 0; t < 4; ++t)
                kb[c][t] = *reinterpret_cast<const bf16x8*>(
                    Ka + (size_t)(j0 + t*16 + lo)*96 + c*32 + hi*8);

        // --- S = Qa . Ka^T ---
        f32x4 s[4];
        #pragma unroll
        for (int t = 0; t < 4; ++t) s[t] = (f32x4){0.f,0.f,0.f,0.f};
        #pragma unroll
        for (int c = 0; c < 3; ++c)
            #pragma unroll
            for (int t = 0; t < 4; ++t)
                s[t] = __builtin_amdgcn_mfma_f32_16x16x32_bf16(qfr[c], kb[c][t], s[t], 0, 0, 0);

        // --- issue ALL 10 V-fragment loads; softmax below hides their latency ---
        bf16x8 vb[2][5];
        #pragma unroll
        for (int kk = 0; kk < 2; ++kk)
            #pragma unroll
            for (int dt = 0; dt < 5; ++dt)
                vb[kk][dt] = *reinterpret_cast<const bf16x8*>(
                    Vt + (size_t)(dt*16 + lo)*N_ + j0 + kk*32 + hi*8);

        // --- online softmax; rows r: i = hi*4 + r, cols j = t*16 + lo ---
        float scl[4];
        #pragma unroll
        for (int r = 0; r < 4; ++r) {
            float v = fmaxf(fmaxf(s[0][r], s[1][r]), fmaxf(s[2][r], s[3][r]));
            v = fmaxf(v, __shfl_xor(v, 1));
            v = fmaxf(v, __shfl_xor(v, 2));
            v = fmaxf(v, __shfl_xor(v, 4));
            v = fmaxf(v, __shfl_xor(v, 8));
            float mn = fmaxf(m[r], v);
            scl[r] = __expf(m[r] - mn);
            m[r] = mn;
        }
        float ps[4] = {0.f,0.f,0.f,0.f};
        #pragma unroll
        for (int t = 0; t < 4; ++t) {
            #pragma unroll
            for (int r = 0; r < 4; ++r) {
                float p = __expf(s[t][r] - m[r]);
                ps[r] += p;
                sP[wid][(hi*4 + r)*VPAD + t*16 + lo] = f2bf(p);
            }
        }
        #pragma unroll
        for (int r = 0; r < 4; ++r) {
            float v = ps[r];
            v += __shfl_xor(v, 1);
            v += __shfl_xor(v, 2);
            v += __shfl_xor(v, 4);
            v += __shfl_xor(v, 8);
            l[r] = l[r]*scl[r] + v;
        }
        #pragma unroll
        for (int d = 0; d < 5; ++d)
            #pragma unroll
            for (int r = 0; r < 4; ++r) acc[d][r] *= scl[r];

        // --- PV: O += P . V  (V already in registers) ---
        #pragma unroll
        for (int kk = 0; kk < 2; ++kk) {
            bf16x8 pa = *reinterpret_cast<const bf16x8*>(
                &sP[wid][lo*VPAD + kk*32 + hi*8]);
            #pragma unroll
            for (int dt = 0; dt < 5; ++dt)
                acc[dt] = __builtin_amdgcn_mfma_f32_16x16x32_bf16(pa, vb[kk][dt], acc[dt], 0, 0, 0);
        }
    }

    // 4-way k-split merge through LDS
    if (kq > 0) {
        #pragma unroll
        for (int r = 0; r < 4; ++r) {
            int rl = hi*4 + r;
            #pragma unroll
            for (int dt = 0; dt < 5; ++dt)
                sAcc[kq-1][qh][rl][dt*16 + lo] = acc[dt][r];
            if (lo == 0) { sML[kq-1][qh][rl][0] = m[r]; sML[kq-1][qh][rl][1] = l[r]; }
        }
    }
    __syncthreads();
    if (kq == 0) {
        float* ws_rs = ws + OFF_RS + (size_t)bh*N_*DH_;
        float* ws_rp = ws + OFF_RP + (size_t)bh*N_*12;
        #pragma unroll
        for (int r = 0; r < 4; ++r) {
            int rl = hi*4 + r;
            float mp[3], lp[3];
            float mm = m[r];
            #pragma unroll
            for (int p = 0; p < 3; ++p) {
                mp[p] = sML[p][qh][rl][0];
                lp[p] = sML[p][qh][rl][1];
                mm = fmaxf(mm, mp[p]);
            }
            float f0 = __expf(m[r] - mm);
            float Lsum = l[r]*f0;
            float fp[3];
            #pragma unroll
            for (int p = 0; p < 3; ++p) {
                fp[p] = __expf(mp[p] - mm);
                Lsum += lp[p]*fp[p];
            }
            float inv = 1.f / Lsum;
            int i = q0 + mrow + rl;
            #pragma unroll
            for (int dt = 0; dt < 5; ++dt) {
                float val = acc[dt][r]*f0;
                #pragma unroll
                for (int p = 0; p < 3; ++p)
                    val += sAcc[p][qh][rl][dt*16 + lo]*fp[p];
                val *= inv;
                int d = dt*16 + lo;
                if (d < 64)
                    ws_rs[(size_t)i*DH_ + d] = val;
                else if (d - 64 < 12)
                    ws_rp[(size_t)i*12 + (d - 64)] = val;
            }
        }
    }
}

// ---------------------------------------------------------------------------
// K4a: finalize features -> fb[2048][640] bf16. grid = 256, block = 256.
// ---------------------------------------------------------------------------
__global__ __launch_bounds__(256) void k_fin_prep(
    const float* __restrict__ rotations,
    const float* __restrict__ translations,
    const float* __restrict__ ws,
    unsigned short* __restrict__ fb)
{
    __shared__ float sF[8][FDIM];
    const int tid = threadIdx.x;
    const int row0 = blockIdx.x * 8;
    const int b = row0 >> 10;
    const float* ws_rs = ws + OFF_RS;
    const float* ws_rp = ws + OFF_RP;

    for (int i = tid; i < 8*512; i += 256) {
        int r = i >> 9, f = i & 511;
        int h = f >> 6, c = f & 63;
        int n = (row0 & (N_-1)) + r;
        sF[r][f] = ws_rs[(((size_t)(b*H_ + h))*N_ + n)*DH_ + c];
    }
    {
        int r = tid >> 5;
        int idx = tid & 31;
        int h = idx >> 2, pd = idx & 3;
        int row = row0 + r;
        int n = row & (N_-1);
        const float* rp = ws_rp + (((size_t)(b*H_ + h))*N_ + n)*12 + pd*3;
        const float* R = rotations + (size_t)row*9;
        const float* T = translations + (size_t)row*3;
        float d0 = rp[0] - T[0], d1 = rp[1] - T[1], d2 = rp[2] - T[2];
        float l0 = R[0]*d0 + R[3]*d1 + R[6]*d2;
        float l1 = R[1]*d0 + R[4]*d1 + R[7]*d2;
        float l2 = R[2]*d0 + R[5]*d1 + R[8]*d2;
        sF[r][512 + h*12 + pd*3 + 0] = l0;
        sF[r][512 + h*12 + pd*3 + 1] = l1;
        sF[r][512 + h*12 + pd*3 + 2] = l2;
        sF[r][608 + h*4 + pd] = sqrtf(l0*l0 + l1*l1 + l2*l2 + 1e-8f);
    }
    __syncthreads();

    #pragma unroll
    for (int r = 0; r < 8; ++r) {
        for (int f = tid; f < FDIM; f += 256) {
            fb[(size_t)(row0 + r)*FDIM + f] = f2bf(sF[r][f]);
        }
    }
}

// ---------------------------------------------------------------------------
// K4b: output GEMM via MFMA. out[2048][768] = fb . wob^T + bout
// ---------------------------------------------------------------------------
__global__ __launch_bounds__(256) void k_out_mfma(
    const unsigned short* __restrict__ fb,
    const unsigned short* __restrict__ wob,
    const float* __restrict__ bout,
    float* __restrict__ out)
{
    __shared__ unsigned short sAB[2*128*32];
    const int tid  = threadIdx.x;
    const int lane = tid & 63;
    const int wid  = tid >> 6;
    const int mt = blockIdx.x & 15;
    const int nt = blockIdx.x >> 4;
    const int row0 = mt*128;
    const int col0 = nt*128;
    const int wr = (wid >> 1)*64;
    const int wc = (wid & 1)*64;

    f32x4 acc[4][4];
    #pragma unroll
    for (int m = 0; m < 4; ++m)
        #pragma unroll
        for (int n = 0; n < 4; ++n) acc[m][n] = (f32x4){0.f,0.f,0.f,0.f};

    for (int kt = 0; kt < FDIM/32; ++kt) {
        __syncthreads();
        #pragma unroll
        for (int t = 0; t < 4; ++t) {
            int chunk = t*4 + wid;
            int tile  = chunk >> 3;
            int crow  = (chunk & 7) * 16;
            int grow  = (tile ? col0 : row0) + crow + (lane >> 2);
            const unsigned short* gsrc = (tile ? wob : fb)
                + (size_t)grow*FDIM + kt*32 + (lane & 3)*8;
            __builtin_amdgcn_global_load_lds(
                (const __attribute__((address_space(1))) void*)gsrc,
                (__attribute__((address_space(3))) void*)(sAB + chunk*512),
                16, 0, 0);
        }
        __syncthreads();

        bf16x8 a[4], b[4];
        #pragma unroll
        for (int m = 0; m < 4; ++m)
            a[m] = *reinterpret_cast<const bf16x8*>(
                sAB + ((wr + m*16 + (lane & 15))*32 + (lane >> 4)*8));
        #pragma unroll
        for (int n = 0; n < 4; ++n)
            b[n] = *reinterpret_cast<const bf16x8*>(
                sAB + 128*32 + ((wc + n*16 + (lane & 15))*32 + (lane >> 4)*8));
        #pragma unroll
        for (int m = 0; m < 4; ++m)
            #pragma unroll
            for (int n = 0; n < 4; ++n)
                acc[m][n] = __builtin_amdgcn_mfma_f32_16x16x32_bf16(
                    a[m], b[n], acc[m][n], 0, 0, 0);
    }

    #pragma unroll
    for (int n = 0; n < 4; ++n) {
        int o = col0 + wc + n*16 + (lane & 15);
        float bo = bout[o];
        #pragma unroll
        for (int m = 0; m < 4; ++m) {
            #pragma unroll
            for (int j = 0; j < 4; ++j) {
                int r = row0 + wr + m*16 + (lane >> 4)*4 + j;
                out[(size_t)r*DIM_ + o] = acc[m][n][j] + bo;
            }
        }
    }
}

// ---------------------------------------------------------------------------
extern "C" void kernel_launch(void* const* d_in, const int* in_sizes, int n_in,
                              void* d_out, int out_size, void* d_ws, size_t ws_size,
                              hipStream_t stream) {
    const float* x            = (const float*)d_in[0];
    const float* rotations    = (const float*)d_in[1];
    const float* translations = (const float*)d_in[2];
    const float* Wsq          = (const float*)d_in[3];
    const float* Wsk          = (const float*)d_in[4];
    const float* Wsv          = (const float*)d_in[5];
    const float* Wpq          = (const float*)d_in[6];
    const float* Wpk          = (const float*)d_in[7];
    const float* Wpv          = (const float*)d_in[8];
    const float* pweights     = (const float*)d_in[9];
    const float* Wout         = (const float*)d_in[10];
    const float* bout         = (const float*)d_in[11];
    float* out = (float*)d_out;
    float* ws  = (float*)d_ws;

    unsigned short* xb  = (unsigned short*)(ws + OFF_XB);
    unsigned short* wb  = (unsigned short*)(ws + OFF_WB);
    unsigned short* qa  = (unsigned short*)(ws + OFF_QA);
    unsigned short* ka  = (unsigned short*)(ws + OFF_KA);
    unsigned short* vt  = (unsigned short*)(ws + OFF_VT);
    unsigned short* fb  = (unsigned short*)(ws + OFF_FB);
    unsigned short* wob = (unsigned short*)(ws + OFF_WOB);

    k_cvt_x<<<(B_*N_*DIM_/4 + 255)/256, 256, 0, stream>>>(x, xb);
    k_cvt_w<<<(NPAD*DIM_/4 + 255)/256, 256, 0, stream>>>(Wsq, Wsk, Wsv, Wpq, Wpk, Wpv, wb);
    k_proj_mfma<<<16*15, 256, 0, stream>>>(xb, wb, ws);
    k_prep<<<B_*N_, 128, 0, stream>>>(rotations, translations, pweights, ws);
    k_attn_mfma<<<BH_*32, 512, 0, stream>>>(qa, ka, vt, ws);
    // wob overwrites wb region: safe, k_proj_mfma has consumed it (stream order)
    k_cvt_wout<<<(DIM_*FDIM/4 + 255)/256, 256, 0, stream>>>(Wout, wob);
    k_fin_prep<<<B_*N_/8, 256, 0, stream>>>(rotations, translations, ws, fb);
    k_out_mfma<<<16*6, 256, 0, stream>>>(fb, wob, bout, out);
}